// Round 10
// baseline (697.849 us; speedup 1.0000x reference)
//
#include <hip/hip_runtime.h>
#include <hip/hip_bf16.h>

#define ED   256   // embed dim
#define NW   8     // num weights
#define NR   5     // num relations
#define CS   64    // cols per slab family
#define KH   128   // k per slab family (half of ED)
#define NPASS 8    // row-passes per block
#define RPP  256   // rows per pass (8 waves x 32)

typedef float  f32x4  __attribute__((ext_vector_type(4)));
typedef __bf16 bf16x8 __attribute__((ext_vector_type(8)));
typedef unsigned short u16;

__device__ __forceinline__ u16 f2bf(float f) {
    return __builtin_bit_cast(u16, __float2bfloat16(f));
}

__device__ __forceinline__ bf16x8 pack8(f32x4 a, f32x4 b) {
    union { u16 u[8]; bf16x8 v; } r;
    r.u[0] = f2bf(a[0]); r.u[1] = f2bf(a[1]); r.u[2] = f2bf(a[2]); r.u[3] = f2bf(a[3]);
    r.u[4] = f2bf(b[0]); r.u[5] = f2bf(b[1]); r.u[6] = f2bf(b[2]); r.u[7] = f2bf(b[3]);
    return r.v;
}

// ---------------------------------------------------------------------------
// Prep: S_T[r][j][i] = sum_w ws[w,r] * rel[w, i*ED + j]   (bf16, [col][k])
// ---------------------------------------------------------------------------
__global__ void prep_S(const float* __restrict__ rel,
                       const float* __restrict__ ws,
                       u16* __restrict__ S_T) {
    int idx = blockIdx.x * blockDim.x + threadIdx.x;
    if (idx >= ED * ED) return;
    int i = idx & (ED - 1);
    int j = idx >> 8;
    float acc[NR];
#pragma unroll
    for (int r = 0; r < NR; ++r) acc[r] = 0.f;
#pragma unroll
    for (int w = 0; w < NW; ++w) {
        float rv = rel[(size_t)w * ED * ED + (size_t)i * ED + j];
#pragma unroll
        for (int r = 0; r < NR; ++r) acc[r] += rv * ws[w * NR + r];
    }
#pragma unroll
    for (int r = 0; r < NR; ++r)
        S_T[((size_t)r * ED + j) * ED + i] = f2bf(acc[r]);
}

// ---------------------------------------------------------------------------
// Main: 512 thr = 8 waves. Block family (jc, kh): cols jc*64..+64 of S, k-half
// kh*128..+128, for ALL 5 relations -> immutable 80 KB LDS slab, staged ONCE
// (global_load_lds, inverse-swizzled source), one __syncthreads, then ZERO
// barriers: each wave independently streams 8 passes x 32 rows (e1 k-half ->
// 32 VGPRs, e2 cols -> 16 packed VGPRs, 160 MFMA vs slab, fused e2-dot +
// 16-lane shfl reduce, atomicAdd partials). 2 blocks/CU x 8 waves = 16
// waves/CU of fully uncoupled work. XCD-grouped decode: the 4 jc-families of
// the same rows sit on one XCD -> e1 L2/L3 sharing.
// ---------------------------------------------------------------------------
__global__ __launch_bounds__(512, 4) void bilinear_kernel(
    const float* __restrict__ e1, const float* __restrict__ e2,
    const u16* __restrict__ S_T, float* __restrict__ out) {

    __shared__ __align__(16) u16 slab[NR * CS * KH];   // 80 KB exactly

    const int t    = threadIdx.x;
    const int wave = t >> 6;
    const int lane = t & 63;
    const int l15  = lane & 15;
    const int l4   = lane >> 4;

    // family decode, XCD-grouped: same-XCD wgids are contiguous; jc fastest
    const int g    = blockIdx.x;
    const int wgid = (g & 7) * 64 + (g >> 3);     // grid = 512
    const int jc   = wgid & 3;                    // col slab 0..3
    const int kh   = (wgid >> 2) & 1;             // k half 0..1
    const int rg   = wgid >> 3;                   // rowgroup 0..63 (2048 rows)

    // ---- stage the slab once: [r][j 0..63][k-chunk c 0..15 of 16B] ----
    // physical chunk c holds logical chunk c ^ (j&7) (bank swizzle)
#pragma unroll
    for (int q = 0; q < 10; ++q) {
        int idx = q * 512 + t;          // 5120 slots x 16B
        int rj  = idx >> 4;             // r*64 + j
        int c   = idx & 15;
        int j   = rj & 63;
        int r   = rj >> 6;
        int cl  = c ^ (j & 7);
        const u16* gp = S_T + ((size_t)(r * ED + jc * CS + j)) * ED
                            + kh * KH + cl * 8;
        u16* lp = slab + (size_t)(q * 512 + wave * 64) * 8;  // wave-uniform
        __builtin_amdgcn_global_load_lds(
            (const __attribute__((address_space(1))) unsigned int*)gp,
            (__attribute__((address_space(3))) unsigned int*)lp, 16, 0, 0);
    }
    __syncthreads();   // slab ready; read-only from here on. No more barriers.

    for (int pass = 0; pass < NPASS; ++pass) {
        const long rowbase = (long)rg * (NPASS * RPP) + pass * RPP + wave * 32;

        // ---- A: e1 rows (k-half) -> 32 VGPRs ----
        bf16x8 av[2][4];
#pragma unroll
        for (int m = 0; m < 2; ++m) {
            const float* rowp =
                e1 + (rowbase + m * 16 + l15) * ED + kh * KH + l4 * 8;
#pragma unroll
            for (int kb = 0; kb < 4; ++kb) {
                f32x4 a = *(const f32x4*)(rowp + kb * 32);
                f32x4 b = *(const f32x4*)(rowp + kb * 32 + 4);
                av[m][kb] = pack8(a, b);
            }
        }

        // ---- e2 cols (r-invariant) -> 16 packed VGPRs ----
        unsigned e2p[2][4][2];
#pragma unroll
        for (int m = 0; m < 2; ++m)
#pragma unroll
            for (int reg = 0; reg < 4; ++reg) {
                const float* erow =
                    e2 + (rowbase + m * 16 + l4 * 4 + reg) * ED + jc * CS + l15;
#pragma unroll
                for (int h = 0; h < 2; ++h) {
                    float a = erow[(2 * h) * 16];
                    float b = erow[(2 * h + 1) * 16];
                    e2p[m][reg][h] =
                        (unsigned)f2bf(a) | ((unsigned)f2bf(b) << 16);
                }
            }

#pragma unroll
        for (int r = 0; r < NR; ++r) {
            f32x4 acc[2][4];
#pragma unroll
            for (int m = 0; m < 2; ++m)
#pragma unroll
                for (int n = 0; n < 4; ++n)
                    acc[m][n] = f32x4{0.f, 0.f, 0.f, 0.f};

#pragma unroll
            for (int kb = 0; kb < 4; ++kb) {
                bf16x8 bv[4];
#pragma unroll
                for (int n = 0; n < 4; ++n) {
                    int j = n * 16 + l15;                 // slab col
                    int c = (kb * 4 + l4) ^ (j & 7);      // physical chunk
                    bv[n] = *(const bf16x8*)(slab + (size_t)(r * CS + j) * KH
                                                  + c * 8);
                }
#pragma unroll
                for (int m = 0; m < 2; ++m)
#pragma unroll
                    for (int n = 0; n < 4; ++n)
                        acc[m][n] = __builtin_amdgcn_mfma_f32_16x16x32_bf16(
                            av[m][kb], bv[n], acc[m][n], 0, 0, 0);
            }

            // ---- epilogue: dot with e2, reduce over 64 slab cols ----
            // C frag: row = m*16 + l4*4 + reg, col = n*16 + l15
#pragma unroll
            for (int m = 0; m < 2; ++m)
#pragma unroll
                for (int reg = 0; reg < 4; ++reg) {
                    float p = 0.f;
#pragma unroll
                    for (int n = 0; n < 4; ++n) {
                        unsigned u = e2p[m][reg][n >> 1];
                        unsigned bits = (n & 1) ? (u & 0xffff0000u) : (u << 16);
                        p += acc[m][n][reg] * __builtin_bit_cast(float, bits);
                    }
#pragma unroll
                    for (int off = 1; off < 16; off <<= 1)
                        p += __shfl_xor(p, off);
                    if (l15 == 0) {
                        long row = rowbase + m * 16 + l4 * 4 + reg;
                        atomicAdd(&out[row * NR + r], p);
                    }
                }
        }
    }
}

extern "C" void kernel_launch(void* const* d_in, const int* in_sizes, int n_in,
                              void* d_out, int out_size, void* d_ws, size_t ws_size,
                              hipStream_t stream) {
    const float* e1  = (const float*)d_in[0];
    const float* e2  = (const float*)d_in[1];
    const float* rel = (const float*)d_in[2];
    const float* ws  = (const float*)d_in[3];
    float* out = (float*)d_out;
    u16* S_T = (u16*)d_ws;                     // NR*ED*ED bf16 = 640 KB

    prep_S<<<(ED * ED + 255) / 256, 256, 0, stream>>>(rel, ws, S_T);

    hipMemsetAsync(out, 0, (size_t)out_size * sizeof(float), stream);

    // grid = 4 col-slabs x 2 k-halves x 64 rowgroups = 512 blocks
    bilinear_kernel<<<512, 512, 0, stream>>>(e1, e2, S_T, out);
}

// Round 11
// 217.625 us; speedup vs baseline: 3.2067x; 3.2067x over previous
//
#include <hip/hip_runtime.h>
#include <hip/hip_bf16.h>

#define ED   256   // embed dim
#define NW   8     // num weights
#define NR   5     // num relations
#define BM   128   // rows per block
#define BCOL 128   // cols per block (column half)
#define BK   32    // k per stage step -> 8 steps per r, 40 total
#define NSTEP (NR * 8)

typedef float  f32x4  __attribute__((ext_vector_type(4)));
typedef __bf16 bf16x8 __attribute__((ext_vector_type(8)));
typedef unsigned short u16;

__device__ __forceinline__ u16 f2bf(float f) {
    return __builtin_bit_cast(u16, __float2bfloat16(f));
}

__device__ __forceinline__ bf16x8 pack8(f32x4 a, f32x4 b) {
    union { u16 u[8]; bf16x8 v; } r;
    r.u[0] = f2bf(a[0]); r.u[1] = f2bf(a[1]); r.u[2] = f2bf(a[2]); r.u[3] = f2bf(a[3]);
    r.u[4] = f2bf(b[0]); r.u[5] = f2bf(b[1]); r.u[6] = f2bf(b[2]); r.u[7] = f2bf(b[3]);
    return r.v;
}

// ---------------------------------------------------------------------------
// Prep: S_T[r][j][i] = sum_w ws[w,r] * rel[w, i*ED + j]   (bf16, [col][k])
// ---------------------------------------------------------------------------
__global__ void prep_S(const float* __restrict__ rel,
                       const float* __restrict__ ws,
                       u16* __restrict__ S_T) {
    int idx = blockIdx.x * blockDim.x + threadIdx.x;
    if (idx >= ED * ED) return;
    int i = idx & (ED - 1);
    int j = idx >> 8;
    float acc[NR];
#pragma unroll
    for (int r = 0; r < NR; ++r) acc[r] = 0.f;
#pragma unroll
    for (int w = 0; w < NW; ++w) {
        float rv = rel[(size_t)w * ED * ED + (size_t)i * ED + j];
#pragma unroll
        for (int r = 0; r < NR; ++r) acc[r] += rv * ws[w * NR + r];
    }
#pragma unroll
    for (int r = 0; r < NR; ++r)
        S_T[((size_t)r * ED + j) * ED + i] = f2bf(acc[r]);
}

// ---------------------------------------------------------------------------
// Main: 256 thr = 4 waves, R6 schedule with M=64 rows/wave (halved LDS-B
// traffic per row, 2x MFMA per ds_read). Block (bx,ch): rows bx*128..+128,
// cols ch*128..+128. Wave (wr,wc): 64 rows x 64 cols. A (e1, full K=256) in
// 128 VGPRs reused over all r; e2 in a 32 KB bf16 LDS slab (epilogue-only).
// B (S_T) staged through a 4-slot LDS ring (8 KB chunks) via global_load_lds
// + XOR swizzle; counted vmcnt (4 steady / 2 / 0 tail) + raw s_barrier per
// step; stage chunk s+2 while computing s (write-after-read safe on ring-4).
// ---------------------------------------------------------------------------
__global__ __launch_bounds__(256, 2) void bilinear_kernel(
    const float* __restrict__ e1, const float* __restrict__ e2,
    const u16* __restrict__ S_T, float* __restrict__ out) {

    __shared__ __align__(16) u16 Bbuf[4][BCOL * BK];   // 4 x 8 KB ring
    __shared__ __align__(16) u16 E2l[BM * BCOL];       // 32 KB bf16
    __shared__ float Red[NR][BM][2];                   // 5 KB

    const int t    = threadIdx.x;
    const int wave = t >> 6;
    const int lane = t & 63;
    const int l15  = lane & 15;
    const int l4   = lane >> 4;
    const int wr   = wave >> 1;    // row group (64 rows)
    const int wc   = wave & 1;     // col slab (64 cols within the 128)

    // XCD pairing: blocks (bx,0),(bx,1) adjacent on the same XCD L2.
    const int g       = blockIdx.x;
    const int per_xcd = gridDim.x >> 3;
    const int wgid    = (g & 7) * per_xcd + (g >> 3);
    const int ch      = wgid & 1;
    const long b0     = (long)(wgid >> 1) * BM;

    // staging: chunk (rr,kb) -> ring slot b. LDS linear, global pre-swizzled.
    // col j owns 64 B (4 x 16B chunks); physical chunk c holds logical
    // c ^ ((j>>1)&3)  (involution, spreads lanes across bank quads on read).
    auto STAGE = [&](int rr, int kb, int b) {
        const u16* gb = S_T + ((size_t)rr * ED + ch * BCOL) * ED + kb * BK;
#pragma unroll
        for (int q = 0; q < 2; ++q) {
            int s2 = q * 256 + t;        // 512 slots x 16B
            int j  = s2 >> 2;            // col 0..127
            int c  = s2 & 3;             // physical 16B chunk within col
            int cl = c ^ ((j >> 1) & 3); // logical chunk (inverse swizzle)
            const u16* gp = gb + (size_t)j * ED + cl * 8;
            u16* lp = &Bbuf[b][(size_t)(q * 256 + wave * 64) * 8]; // wave-uniform
            __builtin_amdgcn_global_load_lds(
                (const __attribute__((address_space(1))) unsigned int*)gp,
                (__attribute__((address_space(3))) unsigned int*)lp, 16, 0, 0);
        }
    };

    STAGE(0, 0, 0);   // chunk 0
    STAGE(0, 1, 1);   // chunk 1

    // ---- stage e2 tile (f32 -> bf16) into E2l: 128 rows x 128 cols ----
#pragma unroll
    for (int q = 0; q < 16; ++q) {
        int idx = q * 256 + t;           // f32x4 index; 32 per row
        int row = idx >> 5;
        int c4  = idx & 31;
        f32x4 v = *(const f32x4*)(e2 + (b0 + row) * ED + ch * BCOL + c4 * 4);
        ushort4 p = make_ushort4(f2bf(v[0]), f2bf(v[1]), f2bf(v[2]), f2bf(v[3]));
        *(ushort4*)&E2l[row * BCOL + c4 * 4] = p;
    }

    // ---- A-operand: e1 rows (full K=256) -> 128 VGPRs, reused for all r ----
    bf16x8 av[4][8];
#pragma unroll
    for (int m = 0; m < 4; ++m) {
        const float* rowp = e1 + (b0 + wr * 64 + m * 16 + l15) * ED + l4 * 8;
#pragma unroll
        for (int kb = 0; kb < 8; ++kb) {
            f32x4 a = *(const f32x4*)(rowp + kb * 32);
            f32x4 b = *(const f32x4*)(rowp + kb * 32 + 4);
            av[m][kb] = pack8(a, b);
        }
    }

    // drain prologue (global loads + E2l ds_writes + chunks 0,1), then sync
    asm volatile("s_waitcnt vmcnt(0) lgkmcnt(0)" ::: "memory");
    __builtin_amdgcn_s_barrier();

#pragma unroll
    for (int r = 0; r < NR; ++r) {
        f32x4 acc[4][4];
#pragma unroll
        for (int m = 0; m < 4; ++m)
#pragma unroll
            for (int n = 0; n < 4; ++n)
                acc[m][n] = f32x4{0.f, 0.f, 0.f, 0.f};

#pragma unroll
        for (int kb = 0; kb < 8; ++kb) {
            const int s = r * 8 + kb;            // static after unroll

            // stage chunk s+2 into ring slot (s+2)&3 (overwrites chunk s-2,
            // whose reads completed before barrier(s-1))
            if (s + 2 < NSTEP) {
                const int sn = s + 2;
                STAGE(sn >> 3, sn & 7, sn & 3);
            }

            // counted wait: chunk s landed when only s+1,s+2 (2x2 loads) fly
            if (s < NSTEP - 2)
                asm volatile("s_waitcnt vmcnt(4)" ::: "memory");
            else if (s == NSTEP - 2)
                asm volatile("s_waitcnt vmcnt(2)" ::: "memory");
            else
                asm volatile("s_waitcnt vmcnt(0)" ::: "memory");
            __builtin_amdgcn_s_barrier();
            __builtin_amdgcn_sched_barrier(0);

            // B fragments from ring slot s&3 (swizzled read)
            bf16x8 bv[4];
#pragma unroll
            for (int n = 0; n < 4; ++n) {
                int j  = wc * 64 + n * 16 + l15;             // local col
                int lb = j * (BK * 2) + l4 * 16;             // logical byte
                int pb = lb ^ (((j >> 1) & 3) << 4);         // physical byte
                bv[n] = *(const bf16x8*)((const char*)Bbuf[s & 3] + pb);
            }
#pragma unroll
            for (int m = 0; m < 4; ++m)
#pragma unroll
                for (int n = 0; n < 4; ++n)
                    acc[m][n] = __builtin_amdgcn_mfma_f32_16x16x32_bf16(
                        av[m][kb], bv[n], acc[m][n], 0, 0, 0);
        }

        // ---- epilogue r: dot with e2 (LDS), 16-lane reduce, stash ----
        // C frag: row = wr*64 + m*16 + l4*4 + reg, col = wc*64 + n*16 + l15
#pragma unroll
        for (int m = 0; m < 4; ++m)
#pragma unroll
            for (int reg = 0; reg < 4; ++reg) {
                const int row = wr * 64 + m * 16 + l4 * 4 + reg;
                float p = 0.f;
#pragma unroll
                for (int n = 0; n < 4; ++n) {
                    unsigned bits =
                        (unsigned)E2l[row * BCOL + wc * 64 + n * 16 + l15] << 16;
                    p += acc[m][n][reg] * __builtin_bit_cast(float, bits);
                }
#pragma unroll
                for (int off = 1; off < 16; off <<= 1)
                    p += __shfl_xor(p, off);
                if (l15 == 0) Red[r][row][wc] = p;
            }
    }

    __syncthreads();
    for (int idx = t; idx < BM * NR; idx += 256) {
        int row = idx / NR;
        int r   = idx - row * NR;
        atomicAdd(&out[(b0 + row) * NR + r], Red[r][row][0] + Red[r][row][1]);
    }
}

extern "C" void kernel_launch(void* const* d_in, const int* in_sizes, int n_in,
                              void* d_out, int out_size, void* d_ws, size_t ws_size,
                              hipStream_t stream) {
    const float* e1  = (const float*)d_in[0];
    const float* e2  = (const float*)d_in[1];
    const float* rel = (const float*)d_in[2];
    const float* ws  = (const float*)d_in[3];
    float* out = (float*)d_out;
    u16* S_T = (u16*)d_ws;                     // NR*ED*ED bf16 = 640 KB

    prep_S<<<(ED * ED + 255) / 256, 256, 0, stream>>>(rel, ws, S_T);

    hipMemsetAsync(out, 0, (size_t)out_size * sizeof(float), stream);

    int B = in_sizes[0] / ED;                  // 131072
    int grid = (B / BM) * 2;                   // 2048 (row-tiles x col-halves)
    bilinear_kernel<<<grid, 256, 0, stream>>>(e1, e2, S_T, out);
}